// Round 3
// baseline (405.171 us; speedup 1.0000x reference)
//
#include <hip/hip_runtime.h>
#include <hip/hip_bf16.h>

#define N_ATOMS 20000
#define N_BONDS 200000
#define MAX_DEG 12
#define IN_DIM 256
#define BOND_DIM 128
#define OUT_DIM 512
#define N_HEADS 8
#define HEAD_DIM 64

typedef __attribute__((ext_vector_type(8))) short short8v;
typedef __attribute__((ext_vector_type(4))) float f32x4;

static __device__ __forceinline__ float bf2f(unsigned int u) {
    union { unsigned int i; float f; } c;
    c.i = (u & 0xffffu) << 16;
    return c.f;
}
static __device__ __forceinline__ unsigned short f2bf(float f) {
    union { float f; unsigned int i; } c;
    c.f = f;
    unsigned int x = c.i;
    x += 0x7fffu + ((x >> 16) & 1u);   // round-to-nearest-even
    return (unsigned short)(x >> 16);
}

// ---------------------------------------------------------------------------
// Wt[n][k] = bf16(W[k][n])  (N fixed 512)
// ---------------------------------------------------------------------------
__global__ void wt_kernel(const float* __restrict__ W, unsigned short* __restrict__ Wt,
                          int K) {
    int id = blockIdx.x * 256 + threadIdx.x;
    if (id >= K * 512) return;
    int n = id / K, k = id % K;
    Wt[id] = f2bf(W[(size_t)k * 512 + n]);
}

// ---------------------------------------------------------------------------
// H[m][512] (bf16) = A[m][K] (f32) @ Wt^T + bias.
// B (COLS x K bf16 = 128 KB) resident in LDS for the whole block lifetime.
// 1024 threads = 16 waves (4/SIMD). Stage B once, then stream M-tiles with
// NO barriers. Wave (cg,rg): cols cg*128..+128, rows rg*16..+16 per tile.
// LDS: K/64 panels of [COLS][64k] bf16, XOR-swizzled (proven 0-conflict).
// ---------------------------------------------------------------------------
template<int COLS, int K, int GRIDX>
__global__ __launch_bounds__(1024) void gemm_res_kernel(
    const float* __restrict__ A, const unsigned short* __restrict__ Wt,
    const float* __restrict__ bias, unsigned short* __restrict__ H,
    int M, int ntiles) {
    constexpr int CG = COLS / 128;        // col-groups (waves across N)
    constexpr int RG = 16 / CG;           // row-groups
    constexpr int RPT = RG * 16;          // rows per tile
    constexpr int NKC = K / 32;           // 32-wide k-chunks
    constexpr int PANEL = COLS * 128;     // bytes per 64-k panel

    __shared__ unsigned short Bls[COLS * K];   // 128 KB
    const int tid = threadIdx.x;
    const int by = blockIdx.y;
    const unsigned short* Wb = Wt + (size_t)by * COLS * K;

    // ---- stage full B once: 8192 16B-chunks, 8 per thread, coalesced ----
    #pragma unroll
    for (int i = 0; i < 8; ++i) {
        int c = tid + (i << 10);               // 0..8191
        int n = c / (K / 8);
        int k8 = (c % (K / 8)) << 3;
        uint4 v = *(const uint4*)(Wb + (size_t)n * K + k8);
        int p = k8 >> 6, kl = k8 & 63;
        int byte = p * PANEL + ((((n << 7) + (kl << 1))) ^ ((n & 7) << 4));
        *(uint4*)((char*)Bls + byte) = v;
    }
    __syncthreads();

    const int w = tid >> 6, l = tid & 63;
    const int cg = w % CG, rg = w / CG;
    const int m = l & 15, kg = (l >> 4) << 3;

    // bias is tile-invariant per lane: hoist to regs
    float bv[8];
    #pragma unroll
    for (int nt = 0; nt < 8; ++nt)
        bv[nt] = bias[by * COLS + cg * 128 + nt * 16 + m];

    for (int t = blockIdx.x; t < ntiles; t += GRIDX) {
        const int rowbase = t * RPT + rg * 16;
        const int arow = rowbase + m;
        const float* arp = A + (size_t)(arow < M ? arow : 0) * K;

        f32x4 acc[8] = {};

        #pragma unroll
        for (int kc = 0; kc < NKC; ++kc) {
            const float* p = arp + (kc << 5) + kg;
            float4 a0 = *(const float4*)p;
            float4 a1 = *(const float4*)(p + 4);
            union { unsigned short us[8]; short8v v; } pk;
            pk.us[0] = f2bf(a0.x); pk.us[1] = f2bf(a0.y);
            pk.us[2] = f2bf(a0.z); pk.us[3] = f2bf(a0.w);
            pk.us[4] = f2bf(a1.x); pk.us[5] = f2bf(a1.y);
            pk.us[6] = f2bf(a1.z); pk.us[7] = f2bf(a1.w);

            const char* base = (const char*)Bls + (kc >> 1) * PANEL;
            const int kl = ((kc & 1) << 5) + kg;
            #pragma unroll
            for (int nt = 0; nt < 8; ++nt) {
                int n = cg * 128 + nt * 16 + m;
                short8v b = *(const short8v*)(base +
                    ((((n << 7) + (kl << 1))) ^ ((n & 7) << 4)));
                acc[nt] = __builtin_amdgcn_mfma_f32_16x16x32_bf16(pk.v, b, acc[nt], 0, 0, 0);
            }
        }

        // ---- epilogue: C row = (l>>4)*4 + r, col = l&15 (verified) ----
        const int rstore = rowbase + ((l >> 4) << 2);
        #pragma unroll
        for (int nt = 0; nt < 8; ++nt) {
            int col = by * COLS + cg * 128 + nt * 16 + m;
            #pragma unroll
            for (int r = 0; r < 4; ++r) {
                int grow = rstore + r;
                if (grow < M) H[(size_t)grow * 512 + col] = f2bf(acc[nt][r] + bv[nt]);
            }
        }
    }
}

// ---------------------------------------------------------------------------
// Fused gather + attention + softmax(deg) + weighted sum.
// One wave per atom; lane l owns channels [l*8, l*8+8) = head l>>3.
// Uniform control flow (predicated mask) so the compiler pipelines gathers.
// ---------------------------------------------------------------------------
__global__ __launch_bounds__(256) void attn_kernel(
    const unsigned short* __restrict__ hA,
    const unsigned short* __restrict__ hB,
    const float* __restrict__ att_src,
    const float* __restrict__ att_dst,
    const float* __restrict__ att_edge,
    const int* __restrict__ a2a,
    const int* __restrict__ a2b,
    float* __restrict__ out) {
    const int w = threadIdx.x >> 6;
    const int l = threadIdx.x & 63;
    const int n = blockIdx.x * 4 + w;
    if (n >= N_ATOMS) return;

    float as[8], ad[8], ae[8];
    {
        float4 v0 = *(const float4*)(att_src + l * 8);
        float4 v1 = *(const float4*)(att_src + l * 8 + 4);
        as[0]=v0.x; as[1]=v0.y; as[2]=v0.z; as[3]=v0.w;
        as[4]=v1.x; as[5]=v1.y; as[6]=v1.z; as[7]=v1.w;
        v0 = *(const float4*)(att_dst + l * 8);
        v1 = *(const float4*)(att_dst + l * 8 + 4);
        ad[0]=v0.x; ad[1]=v0.y; ad[2]=v0.z; ad[3]=v0.w;
        ad[4]=v1.x; ad[5]=v1.y; ad[6]=v1.z; ad[7]=v1.w;
        v0 = *(const float4*)(att_edge + l * 8);
        v1 = *(const float4*)(att_edge + l * 8 + 4);
        ae[0]=v0.x; ae[1]=v0.y; ae[2]=v0.z; ae[3]=v0.w;
        ae[4]=v1.x; ae[5]=v1.y; ae[6]=v1.z; ae[7]=v1.w;
    }

    // score_src from own row
    float s_src;
    {
        uint4 u = *(const uint4*)(hA + (size_t)n * 512 + l * 8);
        float p = bf2f(u.x) * as[0] + bf2f(u.x >> 16) * as[1]
                + bf2f(u.y) * as[2] + bf2f(u.y >> 16) * as[3]
                + bf2f(u.z) * as[4] + bf2f(u.z >> 16) * as[5]
                + bf2f(u.w) * as[6] + bf2f(u.w >> 16) * as[7];
        p += __shfl_xor(p, 1);
        p += __shfl_xor(p, 2);
        p += __shfl_xor(p, 4);
        s_src = p;
    }

    float mrun = -1e30f, lsum = 0.f;
    float acc[8];
    #pragma unroll
    for (int j = 0; j < 8; ++j) acc[j] = 0.f;

    const int* pa = a2a + n * MAX_DEG;
    const int* pb = a2b + n * MAX_DEG;

    #pragma unroll 4
    for (int d = 0; d < MAX_DEG; ++d) {
        const int ia = pa[d];
        const int ib = pb[d];
        const bool valid = (ia != 0);
        uint4 ua = *(const uint4*)(hA + (size_t)ia * 512 + l * 8);
        uint4 ub = *(const uint4*)(hB + (size_t)ib * 512 + l * 8);
        float fa[8], fb[8];
        fa[0]=bf2f(ua.x); fa[1]=bf2f(ua.x>>16); fa[2]=bf2f(ua.y); fa[3]=bf2f(ua.y>>16);
        fa[4]=bf2f(ua.z); fa[5]=bf2f(ua.z>>16); fa[6]=bf2f(ua.w); fa[7]=bf2f(ua.w>>16);
        fb[0]=bf2f(ub.x); fb[1]=bf2f(ub.x>>16); fb[2]=bf2f(ub.y); fb[3]=bf2f(ub.y>>16);
        fb[4]=bf2f(ub.z); fb[5]=bf2f(ub.z>>16); fb[6]=bf2f(ub.w); fb[7]=bf2f(ub.w>>16);

        float p = 0.f;
        #pragma unroll
        for (int j = 0; j < 8; ++j) p += fa[j] * ad[j] + fb[j] * ae[j];
        p += __shfl_xor(p, 1);
        p += __shfl_xor(p, 2);
        p += __shfl_xor(p, 4);

        float sc = s_src + p;
        sc = sc > 0.f ? sc : 0.2f * sc;         // leaky_relu(0.2)

        float mn = valid ? fmaxf(mrun, sc) : mrun;
        float scale = __expf(mrun - mn);        // ==1 when masked (mn==mrun)
        float pw = valid ? __expf(sc - mn) : 0.f;
        lsum = lsum * scale + pw;
        #pragma unroll
        for (int j = 0; j < 8; ++j)
            acc[j] = acc[j] * scale + pw * (fa[j] + fb[j]);
        mrun = mn;
    }

    float inv = lsum > 0.f ? 1.f / lsum : 0.f;
    float4 o0, o1;
    o0.x = acc[0]*inv; o0.y = acc[1]*inv; o0.z = acc[2]*inv; o0.w = acc[3]*inv;
    o1.x = acc[4]*inv; o1.y = acc[5]*inv; o1.z = acc[6]*inv; o1.w = acc[7]*inv;
    float* dst = out + (size_t)n * 512 + l * 8;
    *(float4*)dst = o0;
    *(float4*)(dst + 4) = o1;
}

// ---------------------------------------------------------------------------
extern "C" void kernel_launch(void* const* d_in, const int* in_sizes, int n_in,
                              void* d_out, int out_size, void* d_ws, size_t ws_size,
                              hipStream_t stream) {
    const float* x        = (const float*)d_in[0];
    const float* edge     = (const float*)d_in[1];
    const float* W_atom   = (const float*)d_in[2];
    const float* b_atom   = (const float*)d_in[3];
    const float* W_bond   = (const float*)d_in[4];
    const float* b_bond   = (const float*)d_in[5];
    const float* att_src  = (const float*)d_in[6];
    const float* att_dst  = (const float*)d_in[7];
    const float* att_edge = (const float*)d_in[8];
    const int*   a2a      = (const int*)d_in[9];
    const int*   a2b      = (const int*)d_in[10];
    float* out = (float*)d_out;

    char* ws = (char*)d_ws;
    unsigned short* hA  = (unsigned short*)ws;                               // 20,480,000 B
    unsigned short* hB  = (unsigned short*)(ws + 20480000);                  // 204,800,000 B
    unsigned short* WtA = (unsigned short*)(ws + 20480000 + 204800000);      // 262,144 B
    unsigned short* WtB = WtA + 512 * 256;                                   // 131,072 B

    wt_kernel<<<(512 * 256 + 255) / 256, 256, 0, stream>>>(W_atom, WtA, 256);
    wt_kernel<<<(512 * 128 + 255) / 256, 256, 0, stream>>>(W_bond, WtB, 128);

    // atoms: COLS=256 (grid.y=2 halves of N), K=256, 157 tiles of 128 rows
    gemm_res_kernel<256, 256, 79><<<dim3(79, 2), 1024, 0, stream>>>(
        x, WtA, b_atom, hA, N_ATOMS, 157);
    // bonds: COLS=512, K=128, 3125 tiles of 64 rows, 256 persistent blocks
    gemm_res_kernel<512, 128, 256><<<dim3(256, 1), 1024, 0, stream>>>(
        edge, WtB, b_bond, hB, N_BONDS, 3125);

    attn_kernel<<<(N_ATOMS + 3) / 4, 256, 0, stream>>>(
        hA, hB, att_src, att_dst, att_edge, a2a, a2b, out);
}

// Round 4
// 262.849 us; speedup vs baseline: 1.5415x; 1.5415x over previous
//
#include <hip/hip_runtime.h>
#include <hip/hip_bf16.h>

#define N_ATOMS 20000
#define N_BONDS 200000
#define MAX_DEG 12
#define IN_DIM 256
#define BOND_DIM 128
#define OUT_DIM 512
#define N_HEADS 8
#define HEAD_DIM 64

typedef __attribute__((ext_vector_type(8))) short short8v;
typedef __attribute__((ext_vector_type(4))) float f32x4;

static __device__ __forceinline__ float bf2f(unsigned int u) {
    union { unsigned int i; float f; } c;
    c.i = (u & 0xffffu) << 16;
    return c.f;
}
static __device__ __forceinline__ unsigned short f2bf(float f) {
    union { float f; unsigned int i; } c;
    c.f = f;
    unsigned int x = c.i;
    x += 0x7fffu + ((x >> 16) & 1u);   // round-to-nearest-even
    return (unsigned short)(x >> 16);
}

// ---------------------------------------------------------------------------
// Wt[n][k] = bf16(W[k][n])  (N fixed 512)
// ---------------------------------------------------------------------------
__global__ void wt_kernel(const float* __restrict__ W, unsigned short* __restrict__ Wt,
                          int K) {
    int id = blockIdx.x * 256 + threadIdx.x;
    if (id >= K * 512) return;
    int n = id / K, k = id % K;
    Wt[id] = f2bf(W[(size_t)k * 512 + n]);
}

// ---------------------------------------------------------------------------
// H[m][512] (bf16) = A[m][K] (f32) @ Wt^T + bias.  Tiles 64x64x64, 4 waves.
// Round-1 structure (proven: 88% occ, 0 bank conflicts) + XCD-chunked swizzle:
// the 8 column-siblings of each row-tile run consecutively on the SAME XCD,
// so the A tile is fetched once per XCD-L2 instead of 8x from HBM.
// nbm*8 must be divisible by 8 (always true).
// ---------------------------------------------------------------------------
__global__ __launch_bounds__(256) void gemm_kernel(
    const float* __restrict__ A, const unsigned short* __restrict__ Wt,
    const float* __restrict__ bias, unsigned short* __restrict__ H,
    int M, int K, int nbm) {
    __shared__ unsigned short Als[64 * 64];
    __shared__ unsigned short Bls[64 * 64];
    const int t = threadIdx.x;
    // ---- bijective XCD-chunked swizzle (m204, r==0 case) ----
    const int q = nbm;                       // nwg/8
    const int wgid = (blockIdx.x & 7) * q + (blockIdx.x >> 3);
    const int bn = wgid & 7;                 // 8 col tiles (N=512)
    const int bm = wgid >> 3;
    const int w = t >> 6;                    // wave 0..3
    const int l = t & 63;

    f32x4 acc[4] = {};

    const int nk = K >> 6;
    for (int kk = 0; kk < nk; ++kk) {
        // ---- stage A tile [64 m][64 k] f32 -> bf16, XOR-swizzled ----
        #pragma unroll
        for (int i = 0; i < 2; ++i) {
            int c = t + i * 256;           // 0..511
            int row = c >> 3;              // 0..63
            int k8 = (c & 7) << 3;         // 0,8,..,56
            int grow = (bm << 6) + row;
            float f[8];
            if (grow < M) {
                const float* src = A + (size_t)grow * K + (kk << 6) + k8;
                float4 v0 = *(const float4*)src;
                float4 v1 = *(const float4*)(src + 4);
                f[0] = v0.x; f[1] = v0.y; f[2] = v0.z; f[3] = v0.w;
                f[4] = v1.x; f[5] = v1.y; f[6] = v1.z; f[7] = v1.w;
            } else {
                #pragma unroll
                for (int j = 0; j < 8; ++j) f[j] = 0.f;
            }
            union { unsigned short us[8]; uint4 v; } pk;
            #pragma unroll
            for (int j = 0; j < 8; ++j) pk.us[j] = f2bf(f[j]);
            int byte = ((row << 7) + (k8 << 1)) ^ ((row & 7) << 4);
            *(uint4*)((char*)Als + byte) = pk.v;
        }
        // ---- stage B tile [64 n][64 k] bf16 (from Wt), XOR-swizzled ----
        #pragma unroll
        for (int i = 0; i < 2; ++i) {
            int c = t + i * 256;
            int row = c >> 3;              // n within tile
            int k8 = (c & 7) << 3;
            int gn = (bn << 6) + row;      // < 512 always
            uint4 v = *(const uint4*)(Wt + (size_t)gn * K + (kk << 6) + k8);
            int byte = ((row << 7) + (k8 << 1)) ^ ((row & 7) << 4);
            *(uint4*)((char*)Bls + byte) = v;
        }
        __syncthreads();

        const int m = l & 15;
        const int kg = (l >> 4) << 3;
        #pragma unroll
        for (int ks = 0; ks < 2; ++ks) {
            int kcol = (ks << 5) + kg;
            int arow = (w << 4) + m;
            short8v a = *(short8v*)((char*)Als +
                (((arow << 7) + (kcol << 1)) ^ ((arow & 7) << 4)));
            #pragma unroll
            for (int nt = 0; nt < 4; ++nt) {
                int nrow = (nt << 4) + m;
                short8v b = *(short8v*)((char*)Bls +
                    (((nrow << 7) + (kcol << 1)) ^ ((nrow & 7) << 4)));
                acc[nt] = __builtin_amdgcn_mfma_f32_16x16x32_bf16(a, b, acc[nt], 0, 0, 0);
            }
        }
        __syncthreads();
    }

    // ---- epilogue: C row = (l>>4)*4 + r, col = l&15 (verified layout) ----
    const int m = l & 15;
    const int rbase = (bm << 6) + (w << 4) + ((l >> 4) << 2);
    #pragma unroll
    for (int nt = 0; nt < 4; ++nt) {
        int col = (bn << 6) + (nt << 4) + m;
        float bv = bias[col];
        #pragma unroll
        for (int r = 0; r < 4; ++r) {
            int grow = rbase + r;
            if (grow < M) H[(size_t)grow * 512 + col] = f2bf(acc[nt][r] + bv);
        }
    }
}

// ---------------------------------------------------------------------------
// Fused gather + attention + softmax(deg) + weighted sum.
// One wave per atom; lane l owns channels [l*8, l*8+8) = head l>>3.
// Uniform control flow (predicated mask) so the compiler pipelines gathers.
// ---------------------------------------------------------------------------
__global__ __launch_bounds__(256) void attn_kernel(
    const unsigned short* __restrict__ hA,
    const unsigned short* __restrict__ hB,
    const float* __restrict__ att_src,
    const float* __restrict__ att_dst,
    const float* __restrict__ att_edge,
    const int* __restrict__ a2a,
    const int* __restrict__ a2b,
    float* __restrict__ out) {
    const int w = threadIdx.x >> 6;
    const int l = threadIdx.x & 63;
    const int n = blockIdx.x * 4 + w;
    if (n >= N_ATOMS) return;

    float as[8], ad[8], ae[8];
    {
        float4 v0 = *(const float4*)(att_src + l * 8);
        float4 v1 = *(const float4*)(att_src + l * 8 + 4);
        as[0]=v0.x; as[1]=v0.y; as[2]=v0.z; as[3]=v0.w;
        as[4]=v1.x; as[5]=v1.y; as[6]=v1.z; as[7]=v1.w;
        v0 = *(const float4*)(att_dst + l * 8);
        v1 = *(const float4*)(att_dst + l * 8 + 4);
        ad[0]=v0.x; ad[1]=v0.y; ad[2]=v0.z; ad[3]=v0.w;
        ad[4]=v1.x; ad[5]=v1.y; ad[6]=v1.z; ad[7]=v1.w;
        v0 = *(const float4*)(att_edge + l * 8);
        v1 = *(const float4*)(att_edge + l * 8 + 4);
        ae[0]=v0.x; ae[1]=v0.y; ae[2]=v0.z; ae[3]=v0.w;
        ae[4]=v1.x; ae[5]=v1.y; ae[6]=v1.z; ae[7]=v1.w;
    }

    // score_src from own row
    float s_src;
    {
        uint4 u = *(const uint4*)(hA + (size_t)n * 512 + l * 8);
        float p = bf2f(u.x) * as[0] + bf2f(u.x >> 16) * as[1]
                + bf2f(u.y) * as[2] + bf2f(u.y >> 16) * as[3]
                + bf2f(u.z) * as[4] + bf2f(u.z >> 16) * as[5]
                + bf2f(u.w) * as[6] + bf2f(u.w >> 16) * as[7];
        p += __shfl_xor(p, 1);
        p += __shfl_xor(p, 2);
        p += __shfl_xor(p, 4);
        s_src = p;
    }

    float mrun = -1e30f, lsum = 0.f;
    float acc[8];
    #pragma unroll
    for (int j = 0; j < 8; ++j) acc[j] = 0.f;

    const int* pa = a2a + n * MAX_DEG;
    const int* pb = a2b + n * MAX_DEG;

    #pragma unroll 4
    for (int d = 0; d < MAX_DEG; ++d) {
        const int ia = pa[d];
        const int ib = pb[d];
        const bool valid = (ia != 0);
        uint4 ua = *(const uint4*)(hA + (size_t)ia * 512 + l * 8);
        uint4 ub = *(const uint4*)(hB + (size_t)ib * 512 + l * 8);
        float fa[8], fb[8];
        fa[0]=bf2f(ua.x); fa[1]=bf2f(ua.x>>16); fa[2]=bf2f(ua.y); fa[3]=bf2f(ua.y>>16);
        fa[4]=bf2f(ua.z); fa[5]=bf2f(ua.z>>16); fa[6]=bf2f(ua.w); fa[7]=bf2f(ua.w>>16);
        fb[0]=bf2f(ub.x); fb[1]=bf2f(ub.x>>16); fb[2]=bf2f(ub.y); fb[3]=bf2f(ub.y>>16);
        fb[4]=bf2f(ub.z); fb[5]=bf2f(ub.z>>16); fb[6]=bf2f(ub.w); fb[7]=bf2f(ub.w>>16);

        float p = 0.f;
        #pragma unroll
        for (int j = 0; j < 8; ++j) p += fa[j] * ad[j] + fb[j] * ae[j];
        p += __shfl_xor(p, 1);
        p += __shfl_xor(p, 2);
        p += __shfl_xor(p, 4);

        float sc = s_src + p;
        sc = sc > 0.f ? sc : 0.2f * sc;         // leaky_relu(0.2)

        float mn = valid ? fmaxf(mrun, sc) : mrun;
        float scale = __expf(mrun - mn);        // ==1 when masked (mn==mrun)
        float pw = valid ? __expf(sc - mn) : 0.f;
        lsum = lsum * scale + pw;
        #pragma unroll
        for (int j = 0; j < 8; ++j)
            acc[j] = acc[j] * scale + pw * (fa[j] + fb[j]);
        mrun = mn;
    }

    float inv = lsum > 0.f ? 1.f / lsum : 0.f;
    float4 o0, o1;
    o0.x = acc[0]*inv; o0.y = acc[1]*inv; o0.z = acc[2]*inv; o0.w = acc[3]*inv;
    o1.x = acc[4]*inv; o1.y = acc[5]*inv; o1.z = acc[6]*inv; o1.w = acc[7]*inv;
    float* dst = out + (size_t)n * 512 + l * 8;
    *(float4*)dst = o0;
    *(float4*)(dst + 4) = o1;
}

// ---------------------------------------------------------------------------
extern "C" void kernel_launch(void* const* d_in, const int* in_sizes, int n_in,
                              void* d_out, int out_size, void* d_ws, size_t ws_size,
                              hipStream_t stream) {
    const float* x        = (const float*)d_in[0];
    const float* edge     = (const float*)d_in[1];
    const float* W_atom   = (const float*)d_in[2];
    const float* b_atom   = (const float*)d_in[3];
    const float* W_bond   = (const float*)d_in[4];
    const float* b_bond   = (const float*)d_in[5];
    const float* att_src  = (const float*)d_in[6];
    const float* att_dst  = (const float*)d_in[7];
    const float* att_edge = (const float*)d_in[8];
    const int*   a2a      = (const int*)d_in[9];
    const int*   a2b      = (const int*)d_in[10];
    float* out = (float*)d_out;

    char* ws = (char*)d_ws;
    unsigned short* hA  = (unsigned short*)ws;                               // 20,480,000 B
    unsigned short* hB  = (unsigned short*)(ws + 20480000);                  // 204,800,000 B
    unsigned short* WtA = (unsigned short*)(ws + 20480000 + 204800000);      // 262,144 B
    unsigned short* WtB = WtA + 512 * 256;                                   // 131,072 B

    wt_kernel<<<(512 * 256 + 255) / 256, 256, 0, stream>>>(W_atom, WtA, 256);
    wt_kernel<<<(512 * 128 + 255) / 256, 256, 0, stream>>>(W_bond, WtB, 128);

    // atoms: 313 row-tiles x 8 col-tiles = 2504 blocks (divisible by 8)
    gemm_kernel<<<313 * 8, 256, 0, stream>>>(x, WtA, b_atom, hA, N_ATOMS, 256, 313);
    // bonds: 3125 row-tiles x 8 col-tiles = 25000 blocks (divisible by 8)
    gemm_kernel<<<3125 * 8, 256, 0, stream>>>(edge, WtB, b_bond, hB, N_BONDS, 128, 3125);

    attn_kernel<<<(N_ATOMS + 3) / 4, 256, 0, stream>>>(
        hA, hB, att_src, att_dst, att_edge, a2a, a2b, out);
}

// Round 5
// 229.776 us; speedup vs baseline: 1.7633x; 1.1439x over previous
//
#include <hip/hip_runtime.h>
#include <hip/hip_bf16.h>

#define N_ATOMS 20000
#define N_BONDS 200000
#define MAX_DEG 12
#define IN_DIM 256
#define BOND_DIM 128
#define OUT_DIM 512
#define N_HEADS 8
#define HEAD_DIM 64

typedef __attribute__((ext_vector_type(8))) short short8v;
typedef __attribute__((ext_vector_type(4))) float f32x4;

static __device__ __forceinline__ float bf2f(unsigned int u) {
    union { unsigned int i; float f; } c;
    c.i = (u & 0xffffu) << 16;
    return c.f;
}
static __device__ __forceinline__ unsigned short f2bf(float f) {
    union { float f; unsigned int i; } c;
    c.f = f;
    unsigned int x = c.i;
    x += 0x7fffu + ((x >> 16) & 1u);   // round-to-nearest-even
    return (unsigned short)(x >> 16);
}

// ---------------------------------------------------------------------------
// Wt[n][k] = bf16(W[k][n])  (N fixed 512)
// ---------------------------------------------------------------------------
__global__ void wt_kernel(const float* __restrict__ W, unsigned short* __restrict__ Wt,
                          int K) {
    int id = blockIdx.x * 256 + threadIdx.x;
    if (id >= K * 512) return;
    int n = id / K, k = id % K;
    Wt[id] = f2bf(W[(size_t)k * 512 + n]);
}

// ---------------------------------------------------------------------------
// BOND GEMM: H[m][512] = edge[m][128] @ WtB^T + bias, tile 64x128, K=128
// single-shot. A f32 [64][128] (32KB) + B bf16 [128][128] (32KB) staged with
// global_load_lds w=16 (linear dest + inverse-swizzled SOURCE, rule #21);
// ds_reads apply the same XOR. One barrier. 4 waves: wave w = rows w*16..+16,
// all 128 cols. Bijective XCD swizzle (m204): 4 col-siblings share A in L2.
// ---------------------------------------------------------------------------
__global__ __launch_bounds__(256) void bond_gemm(
    const float* __restrict__ A, const unsigned short* __restrict__ Wt,
    const float* __restrict__ bias, unsigned short* __restrict__ H) {
    __shared__ float Als[64 * 128];               // 32 KB
    __shared__ unsigned short Bls[128 * 128];     // 32 KB
    const int t = threadIdx.x;
    const int w = t >> 6, l = t & 63;

    // ---- bijective XCD-chunked swizzle: NW=12500, q=1562, r=4 ----
    const int xcd = blockIdx.x & 7, lid = blockIdx.x >> 3;
    const int wgid = (xcd < 4 ? xcd * 1563 : 4 * 1563 + (xcd - 4) * 1562) + lid;
    const int bn = wgid & 3;                      // 4 col tiles of 128
    const int bm = wgid >> 2;                     // 0..3124

    // ---- stage A: rows bm*64..+64, f32, 2048 slots of 16B; row = 32 slots.
    // desired LDS image: slot(r,kc) = r*32 + (kc ^ (r&7)); linear dest =>
    // source chunk for slot s: r = s>>5, kc = (s&31) ^ (r&7).
    {
        const char* Ab = (const char*)(A + (size_t)bm * 64 * 128);
        #pragma unroll
        for (int i = 0; i < 8; ++i) {
            int s = (w << 9) + (i << 6) + l;      // 0..2047
            int r = s >> 5;
            int kc = (s & 31) ^ (r & 7);
            const char* src = Ab + r * 512 + kc * 16;
            __builtin_amdgcn_global_load_lds(
                (const __attribute__((address_space(1))) void*)src,
                (__attribute__((address_space(3))) void*)((char*)Als + (((w << 9) + (i << 6)) << 4)),
                16, 0, 0);
        }
    }
    // ---- stage B: WtB rows bn*128..+128, bf16, 2048 slots; row = 16 slots.
    // slot(n,kc) = n*16 + (kc ^ (n&7)); source: n = s>>4, kc = (s&15)^(n&7).
    {
        const char* Wb = (const char*)(Wt + (size_t)bn * 128 * 128);
        #pragma unroll
        for (int i = 0; i < 8; ++i) {
            int s = (w << 9) + (i << 6) + l;      // 0..2047
            int n = s >> 4;
            int kc = (s & 15) ^ (n & 7);
            const char* src = Wb + n * 256 + kc * 16;
            __builtin_amdgcn_global_load_lds(
                (const __attribute__((address_space(1))) void*)src,
                (__attribute__((address_space(3))) void*)((char*)Bls + (((w << 9) + (i << 6)) << 4)),
                16, 0, 0);
        }
    }
    __syncthreads();

    const int m16 = l & 15, g = l >> 4;
    const int arow = (w << 4) + m16;
    const int asw = (arow & 7) << 4;

    f32x4 acc[8] = {};
    #pragma unroll
    for (int ks = 0; ks < 4; ++ks) {
        // a-frag: 8 f32 at k = ks*32 + g*8 (two swizzled 16B reads) -> bf16
        const int ab = arow * 512 + (ks << 7) + (g << 5);
        f32x4 a0 = *(const f32x4*)((const char*)Als + ((ab) ^ asw));
        f32x4 a1 = *(const f32x4*)((const char*)Als + ((ab + 16) ^ asw));
        union { unsigned short us[8]; short8v v; } pk;
        pk.us[0] = f2bf(a0[0]); pk.us[1] = f2bf(a0[1]);
        pk.us[2] = f2bf(a0[2]); pk.us[3] = f2bf(a0[3]);
        pk.us[4] = f2bf(a1[0]); pk.us[5] = f2bf(a1[1]);
        pk.us[6] = f2bf(a1[2]); pk.us[7] = f2bf(a1[3]);

        #pragma unroll
        for (int nt = 0; nt < 8; ++nt) {
            int n = (nt << 4) + m16;
            const short8v b = *(const short8v*)((const char*)Bls +
                ((n * 256 + (ks << 6) + (g << 4)) ^ ((n & 7) << 4)));
            acc[nt] = __builtin_amdgcn_mfma_f32_16x16x32_bf16(pk.v, b, acc[nt], 0, 0, 0);
        }
    }

    // ---- epilogue (verified layout): row = (l>>4)*4 + r, col = l&15 ----
    const int rbase = (bm << 6) + (w << 4) + (g << 2);
    #pragma unroll
    for (int nt = 0; nt < 8; ++nt) {
        int col = (bn << 7) + (nt << 4) + m16;
        float bv = bias[col];
        #pragma unroll
        for (int r = 0; r < 4; ++r)
            H[(size_t)(rbase + r) * 512 + col] = f2bf(acc[nt][r] + bv);
    }
}

// ---------------------------------------------------------------------------
// ATOM GEMM (round-4, proven): tiles 64x64x64, 4 waves, XCD-chunked swizzle.
// ---------------------------------------------------------------------------
__global__ __launch_bounds__(256) void gemm_kernel(
    const float* __restrict__ A, const unsigned short* __restrict__ Wt,
    const float* __restrict__ bias, unsigned short* __restrict__ H,
    int M, int K, int nbm) {
    __shared__ unsigned short Als[64 * 64];
    __shared__ unsigned short Bls[64 * 64];
    const int t = threadIdx.x;
    const int q = nbm;
    const int wgid = (blockIdx.x & 7) * q + (blockIdx.x >> 3);
    const int bn = wgid & 7;
    const int bm = wgid >> 3;
    const int w = t >> 6;
    const int l = t & 63;

    f32x4 acc[4] = {};

    const int nk = K >> 6;
    for (int kk = 0; kk < nk; ++kk) {
        #pragma unroll
        for (int i = 0; i < 2; ++i) {
            int c = t + i * 256;
            int row = c >> 3;
            int k8 = (c & 7) << 3;
            int grow = (bm << 6) + row;
            float f[8];
            if (grow < M) {
                const float* src = A + (size_t)grow * K + (kk << 6) + k8;
                float4 v0 = *(const float4*)src;
                float4 v1 = *(const float4*)(src + 4);
                f[0] = v0.x; f[1] = v0.y; f[2] = v0.z; f[3] = v0.w;
                f[4] = v1.x; f[5] = v1.y; f[6] = v1.z; f[7] = v1.w;
            } else {
                #pragma unroll
                for (int j = 0; j < 8; ++j) f[j] = 0.f;
            }
            union { unsigned short us[8]; uint4 v; } pk;
            #pragma unroll
            for (int j = 0; j < 8; ++j) pk.us[j] = f2bf(f[j]);
            int byte = ((row << 7) + (k8 << 1)) ^ ((row & 7) << 4);
            *(uint4*)((char*)Als + byte) = pk.v;
        }
        #pragma unroll
        for (int i = 0; i < 2; ++i) {
            int c = t + i * 256;
            int row = c >> 3;
            int k8 = (c & 7) << 3;
            int gn = (bn << 6) + row;
            uint4 v = *(const uint4*)(Wt + (size_t)gn * K + (kk << 6) + k8);
            int byte = ((row << 7) + (k8 << 1)) ^ ((row & 7) << 4);
            *(uint4*)((char*)Bls + byte) = v;
        }
        __syncthreads();

        const int m = l & 15;
        const int kg = (l >> 4) << 3;
        #pragma unroll
        for (int ks = 0; ks < 2; ++ks) {
            int kcol = (ks << 5) + kg;
            int arow = (w << 4) + m;
            short8v a = *(short8v*)((char*)Als +
                (((arow << 7) + (kcol << 1)) ^ ((arow & 7) << 4)));
            #pragma unroll
            for (int nt = 0; nt < 4; ++nt) {
                int nrow = (nt << 4) + m;
                short8v b = *(short8v*)((char*)Bls +
                    (((nrow << 7) + (kcol << 1)) ^ ((nrow & 7) << 4)));
                acc[nt] = __builtin_amdgcn_mfma_f32_16x16x32_bf16(a, b, acc[nt], 0, 0, 0);
            }
        }
        __syncthreads();
    }

    const int m = l & 15;
    const int rbase = (bm << 6) + (w << 4) + ((l >> 4) << 2);
    #pragma unroll
    for (int nt = 0; nt < 4; ++nt) {
        int col = (bn << 6) + (nt << 4) + m;
        float bv = bias[col];
        #pragma unroll
        for (int r = 0; r < 4; ++r) {
            int grow = rbase + r;
            if (grow < M) H[(size_t)grow * 512 + col] = f2bf(acc[nt][r] + bv);
        }
    }
}

// ---------------------------------------------------------------------------
// Fused gather + attention + softmax(deg) + weighted sum.
// ---------------------------------------------------------------------------
__global__ __launch_bounds__(256) void attn_kernel(
    const unsigned short* __restrict__ hA,
    const unsigned short* __restrict__ hB,
    const float* __restrict__ att_src,
    const float* __restrict__ att_dst,
    const float* __restrict__ att_edge,
    const int* __restrict__ a2a,
    const int* __restrict__ a2b,
    float* __restrict__ out) {
    const int w = threadIdx.x >> 6;
    const int l = threadIdx.x & 63;
    const int n = blockIdx.x * 4 + w;
    if (n >= N_ATOMS) return;

    float as[8], ad[8], ae[8];
    {
        float4 v0 = *(const float4*)(att_src + l * 8);
        float4 v1 = *(const float4*)(att_src + l * 8 + 4);
        as[0]=v0.x; as[1]=v0.y; as[2]=v0.z; as[3]=v0.w;
        as[4]=v1.x; as[5]=v1.y; as[6]=v1.z; as[7]=v1.w;
        v0 = *(const float4*)(att_dst + l * 8);
        v1 = *(const float4*)(att_dst + l * 8 + 4);
        ad[0]=v0.x; ad[1]=v0.y; ad[2]=v0.z; ad[3]=v0.w;
        ad[4]=v1.x; ad[5]=v1.y; ad[6]=v1.z; ad[7]=v1.w;
        v0 = *(const float4*)(att_edge + l * 8);
        v1 = *(const float4*)(att_edge + l * 8 + 4);
        ae[0]=v0.x; ae[1]=v0.y; ae[2]=v0.z; ae[3]=v0.w;
        ae[4]=v1.x; ae[5]=v1.y; ae[6]=v1.z; ae[7]=v1.w;
    }

    float s_src;
    {
        uint4 u = *(const uint4*)(hA + (size_t)n * 512 + l * 8);
        float p = bf2f(u.x) * as[0] + bf2f(u.x >> 16) * as[1]
                + bf2f(u.y) * as[2] + bf2f(u.y >> 16) * as[3]
                + bf2f(u.z) * as[4] + bf2f(u.z >> 16) * as[5]
                + bf2f(u.w) * as[6] + bf2f(u.w >> 16) * as[7];
        p += __shfl_xor(p, 1);
        p += __shfl_xor(p, 2);
        p += __shfl_xor(p, 4);
        s_src = p;
    }

    float mrun = -1e30f, lsum = 0.f;
    float acc[8];
    #pragma unroll
    for (int j = 0; j < 8; ++j) acc[j] = 0.f;

    const int* pa = a2a + n * MAX_DEG;
    const int* pb = a2b + n * MAX_DEG;

    #pragma unroll 4
    for (int d = 0; d < MAX_DEG; ++d) {
        const int ia = pa[d];
        const int ib = pb[d];
        const bool valid = (ia != 0);
        uint4 ua = *(const uint4*)(hA + (size_t)ia * 512 + l * 8);
        uint4 ub = *(const uint4*)(hB + (size_t)ib * 512 + l * 8);
        float fa[8], fb[8];
        fa[0]=bf2f(ua.x); fa[1]=bf2f(ua.x>>16); fa[2]=bf2f(ua.y); fa[3]=bf2f(ua.y>>16);
        fa[4]=bf2f(ua.z); fa[5]=bf2f(ua.z>>16); fa[6]=bf2f(ua.w); fa[7]=bf2f(ua.w>>16);
        fb[0]=bf2f(ub.x); fb[1]=bf2f(ub.x>>16); fb[2]=bf2f(ub.y); fb[3]=bf2f(ub.y>>16);
        fb[4]=bf2f(ub.z); fb[5]=bf2f(ub.z>>16); fb[6]=bf2f(ub.w); fb[7]=bf2f(ub.w>>16);

        float p = 0.f;
        #pragma unroll
        for (int j = 0; j < 8; ++j) p += fa[j] * ad[j] + fb[j] * ae[j];
        p += __shfl_xor(p, 1);
        p += __shfl_xor(p, 2);
        p += __shfl_xor(p, 4);

        float sc = s_src + p;
        sc = sc > 0.f ? sc : 0.2f * sc;         // leaky_relu(0.2)

        float mn = valid ? fmaxf(mrun, sc) : mrun;
        float scale = __expf(mrun - mn);        // ==1 when masked
        float pw = valid ? __expf(sc - mn) : 0.f;
        lsum = lsum * scale + pw;
        #pragma unroll
        for (int j = 0; j < 8; ++j)
            acc[j] = acc[j] * scale + pw * (fa[j] + fb[j]);
        mrun = mn;
    }

    float inv = lsum > 0.f ? 1.f / lsum : 0.f;
    float4 o0, o1;
    o0.x = acc[0]*inv; o0.y = acc[1]*inv; o0.z = acc[2]*inv; o0.w = acc[3]*inv;
    o1.x = acc[4]*inv; o1.y = acc[5]*inv; o1.z = acc[6]*inv; o1.w = acc[7]*inv;
    float* dst = out + (size_t)n * 512 + l * 8;
    *(float4*)dst = o0;
    *(float4*)(dst + 4) = o1;
}

// ---------------------------------------------------------------------------
extern "C" void kernel_launch(void* const* d_in, const int* in_sizes, int n_in,
                              void* d_out, int out_size, void* d_ws, size_t ws_size,
                              hipStream_t stream) {
    const float* x        = (const float*)d_in[0];
    const float* edge     = (const float*)d_in[1];
    const float* W_atom   = (const float*)d_in[2];
    const float* b_atom   = (const float*)d_in[3];
    const float* W_bond   = (const float*)d_in[4];
    const float* b_bond   = (const float*)d_in[5];
    const float* att_src  = (const float*)d_in[6];
    const float* att_dst  = (const float*)d_in[7];
    const float* att_edge = (const float*)d_in[8];
    const int*   a2a      = (const int*)d_in[9];
    const int*   a2b      = (const int*)d_in[10];
    float* out = (float*)d_out;

    char* ws = (char*)d_ws;
    unsigned short* hA  = (unsigned short*)ws;                               // 20,480,000 B
    unsigned short* hB  = (unsigned short*)(ws + 20480000);                  // 204,800,000 B
    unsigned short* WtA = (unsigned short*)(ws + 20480000 + 204800000);      // 262,144 B
    unsigned short* WtB = WtA + 512 * 256;                                   // 131,072 B

    wt_kernel<<<(512 * 256 + 255) / 256, 256, 0, stream>>>(W_atom, WtA, 256);
    wt_kernel<<<(512 * 128 + 255) / 256, 256, 0, stream>>>(W_bond, WtB, 128);

    // atoms: 313 row-tiles x 8 col-tiles (round-4 kernel)
    gemm_kernel<<<313 * 8, 256, 0, stream>>>(x, WtA, b_atom, hA, N_ATOMS, 256, 313);
    // bonds: 3125 row-tiles x 4 col-tiles = 12500 blocks, new single-shot kernel
    bond_gemm<<<12500, 256, 0, stream>>>(edge, WtB, b_bond, hB);

    attn_kernel<<<(N_ATOMS + 3) / 4, 256, 0, stream>>>(
        hA, hB, att_src, att_dst, att_edge, a2a, a2b, out);
}

// Round 6
// 224.727 us; speedup vs baseline: 1.8029x; 1.0225x over previous
//
#include <hip/hip_runtime.h>
#include <hip/hip_bf16.h>

#define N_ATOMS 20000
#define N_BONDS 200000
#define MAX_DEG 12
#define IN_DIM 256
#define BOND_DIM 128
#define OUT_DIM 512
#define N_HEADS 8
#define HEAD_DIM 64

typedef __attribute__((ext_vector_type(8))) short short8v;
typedef __attribute__((ext_vector_type(4))) float f32x4;

static __device__ __forceinline__ float bf2f(unsigned int u) {
    union { unsigned int i; float f; } c;
    c.i = (u & 0xffffu) << 16;
    return c.f;
}
static __device__ __forceinline__ unsigned short f2bf(float f) {
    union { float f; unsigned int i; } c;
    c.f = f;
    unsigned int x = c.i;
    x += 0x7fffu + ((x >> 16) & 1u);   // round-to-nearest-even
    return (unsigned short)(x >> 16);
}

// ---------------------------------------------------------------------------
// Wt[n][k] = bf16(W[k][n])  (N fixed 512)
// ---------------------------------------------------------------------------
__global__ void wt_kernel(const float* __restrict__ W, unsigned short* __restrict__ Wt,
                          int K) {
    int id = blockIdx.x * 256 + threadIdx.x;
    if (id >= K * 512) return;
    int n = id / K, k = id % K;
    Wt[id] = f2bf(W[(size_t)k * 512 + n]);
}

// ---------------------------------------------------------------------------
// BOND GEMM v2: H[m][512] = edge[m][128] @ WtB^T + bias, tile 64x128, K=128
// single-shot. A is PRIVATE PER WAVE -> loaded straight to registers (per-lane
// 32B chunks matching the MFMA fragment), converted to bf16 in-reg while B
// streams into LDS via global_load_lds w=16 (linear dest + inverse-swizzled
// source, rule #21). LDS = B only (32 KB) -> 4 blocks/CU (launch_bounds(256,4)).
// One barrier. Bijective XCD swizzle (m204): 4 col-siblings share A in L2.
// ---------------------------------------------------------------------------
__global__ __launch_bounds__(256, 4) void bond_gemm(
    const float* __restrict__ A, const unsigned short* __restrict__ Wt,
    const float* __restrict__ bias, unsigned short* __restrict__ H) {
    __shared__ unsigned short Bls[128 * 128];     // 32 KB
    const int t = threadIdx.x;
    const int w = t >> 6, l = t & 63;

    // ---- bijective XCD-chunked swizzle: NW=12500, q=1562, r=4 ----
    const int xcd = blockIdx.x & 7, lid = blockIdx.x >> 3;
    const int wgid = (xcd < 4 ? xcd * 1563 : 4 * 1563 + (xcd - 4) * 1562) + lid;
    const int bn = wgid & 3;                      // 4 col tiles of 128
    const int bm = wgid >> 2;                     // 0..3124

    const int m16 = l & 15, g = l >> 4;
    const int arow = (w << 4) + m16;

    // ---- A: direct global->reg, fragment-shaped (row arow, k = ks*32+g*8) ----
    const float* Ar = A + (size_t)(bm * 64 + arow) * 128 + (g << 3);
    f32x4 a0[4], a1[4];
    #pragma unroll
    for (int ks = 0; ks < 4; ++ks) {
        a0[ks] = *(const f32x4*)(Ar + (ks << 5));
        a1[ks] = *(const f32x4*)(Ar + (ks << 5) + 4);
    }

    // ---- stage B: WtB rows bn*128..+128, bf16, 2048 slots of 16B; 16/row.
    // LDS image: slot(n,kc) = n*16 + (kc ^ (n&7)); linear dest => source
    // chunk for slot s: n = s>>4, kc = (s&15)^(n&7).
    {
        const char* Wb = (const char*)(Wt + (size_t)bn * 128 * 128);
        #pragma unroll
        for (int i = 0; i < 8; ++i) {
            int s = (w << 8) + (i << 5) + (l >> 1);   // hmm-free: see below
            // NOTE: keep the proven r5 mapping: s = w*512 + i*64 + l
            s = (w << 9) + (i << 6) + l;              // 0..2047
            int n = s >> 4;
            int kc = (s & 15) ^ (n & 7);
            const char* src = Wb + n * 256 + kc * 16;
            __builtin_amdgcn_global_load_lds(
                (const __attribute__((address_space(1))) void*)src,
                (__attribute__((address_space(3))) void*)((char*)Bls + (((w << 9) + (i << 6)) << 4)),
                16, 0, 0);
        }
    }

    // ---- convert A to bf16 fragments (overlaps with B's in-flight loads) ----
    short8v afr[4];
    #pragma unroll
    for (int ks = 0; ks < 4; ++ks) {
        union { unsigned short us[8]; short8v v; } pk;
        pk.us[0] = f2bf(a0[ks][0]); pk.us[1] = f2bf(a0[ks][1]);
        pk.us[2] = f2bf(a0[ks][2]); pk.us[3] = f2bf(a0[ks][3]);
        pk.us[4] = f2bf(a1[ks][0]); pk.us[5] = f2bf(a1[ks][1]);
        pk.us[6] = f2bf(a1[ks][2]); pk.us[7] = f2bf(a1[ks][3]);
        afr[ks] = pk.v;
    }

    __syncthreads();

    f32x4 acc[8] = {};
    #pragma unroll
    for (int ks = 0; ks < 4; ++ks) {
        #pragma unroll
        for (int nt = 0; nt < 8; ++nt) {
            int n = (nt << 4) + m16;
            const short8v b = *(const short8v*)((const char*)Bls +
                ((n * 256 + (ks << 6) + (g << 4)) ^ ((n & 7) << 4)));
            acc[nt] = __builtin_amdgcn_mfma_f32_16x16x32_bf16(afr[ks], b, acc[nt], 0, 0, 0);
        }
    }

    // ---- epilogue (verified layout): row = (l>>4)*4 + r, col = l&15 ----
    const int rbase = (bm << 6) + (w << 4) + (g << 2);
    #pragma unroll
    for (int nt = 0; nt < 8; ++nt) {
        int col = (bn << 7) + (nt << 4) + m16;
        float bv = bias[col];
        #pragma unroll
        for (int r = 0; r < 4; ++r)
            H[(size_t)(rbase + r) * 512 + col] = f2bf(acc[nt][r] + bv);
    }
}

// ---------------------------------------------------------------------------
// ATOM GEMM (round-4, proven): tiles 64x64x64, 4 waves, XCD-chunked swizzle.
// ---------------------------------------------------------------------------
__global__ __launch_bounds__(256) void gemm_kernel(
    const float* __restrict__ A, const unsigned short* __restrict__ Wt,
    const float* __restrict__ bias, unsigned short* __restrict__ H,
    int M, int K, int nbm) {
    __shared__ unsigned short Als[64 * 64];
    __shared__ unsigned short Bls[64 * 64];
    const int t = threadIdx.x;
    const int q = nbm;
    const int wgid = (blockIdx.x & 7) * q + (blockIdx.x >> 3);
    const int bn = wgid & 7;
    const int bm = wgid >> 3;
    const int w = t >> 6;
    const int l = t & 63;

    f32x4 acc[4] = {};

    const int nk = K >> 6;
    for (int kk = 0; kk < nk; ++kk) {
        #pragma unroll
        for (int i = 0; i < 2; ++i) {
            int c = t + i * 256;
            int row = c >> 3;
            int k8 = (c & 7) << 3;
            int grow = (bm << 6) + row;
            float f[8];
            if (grow < M) {
                const float* src = A + (size_t)grow * K + (kk << 6) + k8;
                float4 v0 = *(const float4*)src;
                float4 v1 = *(const float4*)(src + 4);
                f[0] = v0.x; f[1] = v0.y; f[2] = v0.z; f[3] = v0.w;
                f[4] = v1.x; f[5] = v1.y; f[6] = v1.z; f[7] = v1.w;
            } else {
                #pragma unroll
                for (int j = 0; j < 8; ++j) f[j] = 0.f;
            }
            union { unsigned short us[8]; uint4 v; } pk;
            #pragma unroll
            for (int j = 0; j < 8; ++j) pk.us[j] = f2bf(f[j]);
            int byte = ((row << 7) + (k8 << 1)) ^ ((row & 7) << 4);
            *(uint4*)((char*)Als + byte) = pk.v;
        }
        #pragma unroll
        for (int i = 0; i < 2; ++i) {
            int c = t + i * 256;
            int row = c >> 3;
            int k8 = (c & 7) << 3;
            int gn = (bn << 6) + row;
            uint4 v = *(const uint4*)(Wt + (size_t)gn * K + (kk << 6) + k8);
            int byte = ((row << 7) + (k8 << 1)) ^ ((row & 7) << 4);
            *(uint4*)((char*)Bls + byte) = v;
        }
        __syncthreads();

        const int m = l & 15;
        const int kg = (l >> 4) << 3;
        #pragma unroll
        for (int ks = 0; ks < 2; ++ks) {
            int kcol = (ks << 5) + kg;
            int arow = (w << 4) + m;
            short8v a = *(short8v*)((char*)Als +
                (((arow << 7) + (kcol << 1)) ^ ((arow & 7) << 4)));
            #pragma unroll
            for (int nt = 0; nt < 4; ++nt) {
                int nrow = (nt << 4) + m;
                short8v b = *(short8v*)((char*)Bls +
                    (((nrow << 7) + (kcol << 1)) ^ ((nrow & 7) << 4)));
                acc[nt] = __builtin_amdgcn_mfma_f32_16x16x32_bf16(a, b, acc[nt], 0, 0, 0);
            }
        }
        __syncthreads();
    }

    const int m = l & 15;
    const int rbase = (bm << 6) + (w << 4) + ((l >> 4) << 2);
    #pragma unroll
    for (int nt = 0; nt < 4; ++nt) {
        int col = (bn << 6) + (nt << 4) + m;
        float bv = bias[col];
        #pragma unroll
        for (int r = 0; r < 4; ++r) {
            int grow = rbase + r;
            if (grow < M) H[(size_t)grow * 512 + col] = f2bf(acc[nt][r] + bv);
        }
    }
}

// ---------------------------------------------------------------------------
// Fused gather + attention + softmax(deg) + weighted sum.
// ---------------------------------------------------------------------------
__global__ __launch_bounds__(256) void attn_kernel(
    const unsigned short* __restrict__ hA,
    const unsigned short* __restrict__ hB,
    const float* __restrict__ att_src,
    const float* __restrict__ att_dst,
    const float* __restrict__ att_edge,
    const int* __restrict__ a2a,
    const int* __restrict__ a2b,
    float* __restrict__ out) {
    const int w = threadIdx.x >> 6;
    const int l = threadIdx.x & 63;
    const int n = blockIdx.x * 4 + w;
    if (n >= N_ATOMS) return;

    float as[8], ad[8], ae[8];
    {
        float4 v0 = *(const float4*)(att_src + l * 8);
        float4 v1 = *(const float4*)(att_src + l * 8 + 4);
        as[0]=v0.x; as[1]=v0.y; as[2]=v0.z; as[3]=v0.w;
        as[4]=v1.x; as[5]=v1.y; as[6]=v1.z; as[7]=v1.w;
        v0 = *(const float4*)(att_dst + l * 8);
        v1 = *(const float4*)(att_dst + l * 8 + 4);
        ad[0]=v0.x; ad[1]=v0.y; ad[2]=v0.z; ad[3]=v0.w;
        ad[4]=v1.x; ad[5]=v1.y; ad[6]=v1.z; ad[7]=v1.w;
        v0 = *(const float4*)(att_edge + l * 8);
        v1 = *(const float4*)(att_edge + l * 8 + 4);
        ae[0]=v0.x; ae[1]=v0.y; ae[2]=v0.z; ae[3]=v0.w;
        ae[4]=v1.x; ae[5]=v1.y; ae[6]=v1.z; ae[7]=v1.w;
    }

    float s_src;
    {
        uint4 u = *(const uint4*)(hA + (size_t)n * 512 + l * 8);
        float p = bf2f(u.x) * as[0] + bf2f(u.x >> 16) * as[1]
                + bf2f(u.y) * as[2] + bf2f(u.y >> 16) * as[3]
                + bf2f(u.z) * as[4] + bf2f(u.z >> 16) * as[5]
                + bf2f(u.w) * as[6] + bf2f(u.w >> 16) * as[7];
        p += __shfl_xor(p, 1);
        p += __shfl_xor(p, 2);
        p += __shfl_xor(p, 4);
        s_src = p;
    }

    float mrun = -1e30f, lsum = 0.f;
    float acc[8];
    #pragma unroll
    for (int j = 0; j < 8; ++j) acc[j] = 0.f;

    const int* pa = a2a + n * MAX_DEG;
    const int* pb = a2b + n * MAX_DEG;

    #pragma unroll 4
    for (int d = 0; d < MAX_DEG; ++d) {
        const int ia = pa[d];
        const int ib = pb[d];
        const bool valid = (ia != 0);
        uint4 ua = *(const uint4*)(hA + (size_t)ia * 512 + l * 8);
        uint4 ub = *(const uint4*)(hB + (size_t)ib * 512 + l * 8);
        float fa[8], fb[8];
        fa[0]=bf2f(ua.x); fa[1]=bf2f(ua.x>>16); fa[2]=bf2f(ua.y); fa[3]=bf2f(ua.y>>16);
        fa[4]=bf2f(ua.z); fa[5]=bf2f(ua.z>>16); fa[6]=bf2f(ua.w); fa[7]=bf2f(ua.w>>16);
        fb[0]=bf2f(ub.x); fb[1]=bf2f(ub.x>>16); fb[2]=bf2f(ub.y); fb[3]=bf2f(ub.y>>16);
        fb[4]=bf2f(ub.z); fb[5]=bf2f(ub.z>>16); fb[6]=bf2f(ub.w); fb[7]=bf2f(ub.w>>16);

        float p = 0.f;
        #pragma unroll
        for (int j = 0; j < 8; ++j) p += fa[j] * ad[j] + fb[j] * ae[j];
        p += __shfl_xor(p, 1);
        p += __shfl_xor(p, 2);
        p += __shfl_xor(p, 4);

        float sc = s_src + p;
        sc = sc > 0.f ? sc : 0.2f * sc;         // leaky_relu(0.2)

        float mn = valid ? fmaxf(mrun, sc) : mrun;
        float scale = __expf(mrun - mn);        // ==1 when masked
        float pw = valid ? __expf(sc - mn) : 0.f;
        lsum = lsum * scale + pw;
        #pragma unroll
        for (int j = 0; j < 8; ++j)
            acc[j] = acc[j] * scale + pw * (fa[j] + fb[j]);
        mrun = mn;
    }

    float inv = lsum > 0.f ? 1.f / lsum : 0.f;
    float4 o0, o1;
    o0.x = acc[0]*inv; o0.y = acc[1]*inv; o0.z = acc[2]*inv; o0.w = acc[3]*inv;
    o1.x = acc[4]*inv; o1.y = acc[5]*inv; o1.z = acc[6]*inv; o1.w = acc[7]*inv;
    float* dst = out + (size_t)n * 512 + l * 8;
    *(float4*)dst = o0;
    *(float4*)(dst + 4) = o1;
}

// ---------------------------------------------------------------------------
extern "C" void kernel_launch(void* const* d_in, const int* in_sizes, int n_in,
                              void* d_out, int out_size, void* d_ws, size_t ws_size,
                              hipStream_t stream) {
    const float* x        = (const float*)d_in[0];
    const float* edge     = (const float*)d_in[1];
    const float* W_atom   = (const float*)d_in[2];
    const float* b_atom   = (const float*)d_in[3];
    const float* W_bond   = (const float*)d_in[4];
    const float* b_bond   = (const float*)d_in[5];
    const float* att_src  = (const float*)d_in[6];
    const float* att_dst  = (const float*)d_in[7];
    const float* att_edge = (const float*)d_in[8];
    const int*   a2a      = (const int*)d_in[9];
    const int*   a2b      = (const int*)d_in[10];
    float* out = (float*)d_out;

    char* ws = (char*)d_ws;
    unsigned short* hA  = (unsigned short*)ws;                               // 20,480,000 B
    unsigned short* hB  = (unsigned short*)(ws + 20480000);                  // 204,800,000 B
    unsigned short* WtA = (unsigned short*)(ws + 20480000 + 204800000);      // 262,144 B
    unsigned short* WtB = WtA + 512 * 256;                                   // 131,072 B

    wt_kernel<<<(512 * 256 + 255) / 256, 256, 0, stream>>>(W_atom, WtA, 256);
    wt_kernel<<<(512 * 128 + 255) / 256, 256, 0, stream>>>(W_bond, WtB, 128);

    // atoms: 313 row-tiles x 8 col-tiles (round-4 kernel)
    gemm_kernel<<<313 * 8, 256, 0, stream>>>(x, WtA, b_atom, hA, N_ATOMS, 256, 313);
    // bonds: 3125 row-tiles x 4 col-tiles = 12500 blocks, A-in-reg kernel
    bond_gemm<<<12500, 256, 0, stream>>>(edge, WtB, b_bond, hB);

    attn_kernel<<<(N_ATOMS + 3) / 4, 256, 0, stream>>>(
        hA, hB, att_src, att_dst, att_edge, a2a, a2b, out);
}